// Round 11
// baseline (845.127 us; speedup 1.0000x reference)
//
#include <hip/hip_runtime.h>

// GCN 3-layer forward, MI355X (gfx950) — R10.
// R10 changes vs R9 (638 us):
//  - GEMM2/GEMM3 fused into the gathers (row-local epilogue dot via LDS-staged W):
//    kills 2 dispatches + the AGG intermediate round-trip (~84 MB traffic).
//  - W1 pre-converted once to bf16 hi/lo MFMA fragments (k_prep_w1): removes
//    per-block conversion VALU + B LDS from the GEMM1 hot loop.

#define NNODES 100000
#define NEDGES 1000000
#define INF 512
#define SCAN_B 512

typedef float f32x4_t __attribute__((ext_vector_type(4)));
typedef short s16x8_t __attribute__((ext_vector_type(8)));

__device__ __forceinline__ unsigned short f2bf(float x) {
  unsigned u = __float_as_uint(x);
  return (unsigned short)((u + 0x7FFFu + ((u >> 16) & 1u)) >> 16);
}
__device__ __forceinline__ float bf2f(unsigned short h) {
  return __uint_as_float(((unsigned)h) << 16);
}

__global__ void k_init(float* __restrict__ deg, int* __restrict__ cnt, int n) {
  int i = blockIdx.x * blockDim.x + threadIdx.x;
  if (i < n) { deg[i] = 1.0f; cnt[i] = 0; }
}

__global__ void k_deg_cnt(const int* __restrict__ dst, const float* __restrict__ ew,
                          float* __restrict__ deg, int* __restrict__ cnt, int E) {
  int e = blockIdx.x * blockDim.x + threadIdx.x;
  if (e < E) {
    int d = dst[e];
    atomicAdd(&deg[d], ew[e]);
    atomicAdd(&cnt[d], 1);
  }
}

// exclusive scan stage 1 + fused dinv (deg -> 1/sqrt(deg))
__global__ __launch_bounds__(SCAN_B) void k_scan1(const int* __restrict__ cnt,
                                                  int* __restrict__ rs,
                                                  int* __restrict__ bsums,
                                                  float* __restrict__ deg, int n) {
  __shared__ int s[SCAN_B];
  const int t = threadIdx.x;
  const int i = blockIdx.x * SCAN_B + t;
  int v = (i < n) ? cnt[i] : 0;
  s[t] = v;
  __syncthreads();
  int acc = v;
#pragma unroll
  for (int off = 1; off < SCAN_B; off <<= 1) {
    int add = (t >= off) ? s[t - off] : 0;
    __syncthreads();
    acc += add;
    s[t] = acc;
    __syncthreads();
  }
  if (i < n) {
    rs[i] = acc - v;
    float d = deg[i];
    deg[i] = d > 0.f ? 1.0f / sqrtf(d) : 0.f;
  }
  if (t == SCAN_B - 1) bsums[blockIdx.x] = acc;
}

__global__ __launch_bounds__(256) void k_scan2(int* __restrict__ bsums, int nb) {
  __shared__ int s[256];
  const int t = threadIdx.x;
  int v = (t < nb) ? bsums[t] : 0;
  s[t] = v;
  __syncthreads();
  int acc = v;
#pragma unroll
  for (int off = 1; off < 256; off <<= 1) {
    int add = (t >= off) ? s[t - off] : 0;
    __syncthreads();
    acc += add;
    s[t] = acc;
    __syncthreads();
  }
  if (t < nb) bsums[t] = acc - v;
}

__global__ void k_scan3(int* __restrict__ rs, const int* __restrict__ bsums,
                        int* __restrict__ cnt, int n, int E) {
  int i = blockIdx.x * blockDim.x + threadIdx.x;
  if (i < n) {
    rs[i] += bsums[i / SCAN_B];
    cnt[i] = 0;
  }
  if (i == 0) rs[n] = E;
}

__global__ void k_fill(const int* __restrict__ src, const int* __restrict__ dst,
                       const float* __restrict__ ew, const float* __restrict__ dinv,
                       const int* __restrict__ rs, int* __restrict__ cur,
                       int2* __restrict__ ep, int E) {
  int e = blockIdx.x * blockDim.x + threadIdx.x;
  if (e < E) {
    const int s = src[e], d = dst[e];
    const int pos = rs[d] + atomicAdd(&cur[d], 1);
    const float nm = dinv[s] * ew[e] * dinv[d];
    ep[pos] = make_int2(s, __float_as_int(nm));
  }
}

// W1[512][64] -> bf16 hi/lo fragments in the exact 16x16x32 MFMA B layout
// (verified by R9's passing run): frag (kstep, coltile bc, lane l) elem i is
// W[kstep*32 + (l>>4)*8 + i][bc*16 + (l&15)].
__global__ __launch_bounds__(256) void k_prep_w1(const float* __restrict__ W,
                                                 s16x8_t* __restrict__ BH,
                                                 s16x8_t* __restrict__ BL) {
  const int t = blockIdx.x * 256 + threadIdx.x;  // 0..4095
  const int kstep = t >> 8, rem = t & 255, bc = rem >> 6, l = rem & 63;
  const int kg = l >> 4, m0 = l & 15;
  s16x8_t bh, blo;
#pragma unroll
  for (int i = 0; i < 8; ++i) {
    const float w = W[(size_t)(kstep * 32 + kg * 8 + i) * 64 + bc * 16 + m0];
    const unsigned short h = f2bf(w);
    bh[i] = (short)h;
    blo[i] = (short)f2bf(w - bf2f(h));
  }
  BH[t] = bh;
  BL[t] = blo;
}

// GEMM1: H[M,64] = A[M,512] @ W1, bf16x3 MFMA, B-frags preconverted in global.
__global__ __launch_bounds__(256) void k_gemm1_mfma(
    const float* __restrict__ A, const s16x8_t* __restrict__ BH,
    const s16x8_t* __restrict__ BL, float* __restrict__ C, int M) {
  __shared__ float As[128][36];
  const int tid = threadIdx.x;
  const int bm = blockIdx.x * 128;
  const int wv = tid >> 6;
  const int l = tid & 63;
  const int m0 = l & 15;
  const int kg = l >> 4;

  f32x4_t acc[2][4];
#pragma unroll
  for (int r = 0; r < 2; ++r)
#pragma unroll
    for (int c = 0; c < 4; ++c) acc[r][c] = (f32x4_t)0.f;

  for (int k0 = 0; k0 < INF; k0 += 32) {
    // B fragment loads (coalesced 16B, L2-hit) — issue early
    s16x8_t bh[4], bl[4];
    const int kbase = (k0 >> 5) * 256 + l;
#pragma unroll
    for (int c = 0; c < 4; ++c) {
      bh[c] = BH[kbase + c * 64];
      bl[c] = BL[kbase + c * 64];
    }
    // stage A tile [128][32] fp32
#pragma unroll
    for (int i = 0; i < 4; ++i) {
      const int idx = i * 256 + tid;
      const int row = idx >> 3;
      const int kq = (idx & 7) << 2;
      const int grow = bm + row;
      float4 v = make_float4(0.f, 0.f, 0.f, 0.f);
      if (grow < M) v = *(const float4*)(A + (size_t)grow * INF + k0 + kq);
      *(float4*)&As[row][kq] = v;
    }
    __syncthreads();

    // A fragments (fp32 -> bf16 hi/lo)
    s16x8_t ahi[2], alo[2];
#pragma unroll
    for (int r = 0; r < 2; ++r) {
      const float* ap = &As[wv * 32 + r * 16 + m0][kg * 8];
      const float4 x0 = *(const float4*)ap;
      const float4 x1 = *(const float4*)(ap + 4);
      const float xs[8] = {x0.x, x0.y, x0.z, x0.w, x1.x, x1.y, x1.z, x1.w};
#pragma unroll
      for (int i = 0; i < 8; ++i) {
        const unsigned short h = f2bf(xs[i]);
        ahi[r][i] = (short)h;
        alo[r][i] = (short)f2bf(xs[i] - bf2f(h));
      }
    }
#pragma unroll
    for (int c = 0; c < 4; ++c) {
#pragma unroll
      for (int r = 0; r < 2; ++r) {
        acc[r][c] = __builtin_amdgcn_mfma_f32_16x16x32_bf16(ahi[r], bh[c], acc[r][c], 0, 0, 0);
        acc[r][c] = __builtin_amdgcn_mfma_f32_16x16x32_bf16(alo[r], bh[c], acc[r][c], 0, 0, 0);
        acc[r][c] = __builtin_amdgcn_mfma_f32_16x16x32_bf16(ahi[r], bl[c], acc[r][c], 0, 0, 0);
      }
    }
    __syncthreads();
  }

#pragma unroll
  for (int r = 0; r < 2; ++r) {
    const int rowbase = bm + wv * 32 + r * 16 + (l >> 4) * 4;
#pragma unroll
    for (int j = 0; j < 4; ++j) {
      const int row = rowbase + j;
      if (row < M) {
#pragma unroll
        for (int c = 0; c < 4; ++c)
          C[(size_t)row * 64 + c * 16 + m0] = acc[r][c][j];
      }
    }
  }
}

// Fused gather + relu(+bias) + [64x64] GEMM. 16 nodes/block, wave owns 4 nodes.
// Row bounces through per-wave LDS (intra-wave RAW -> compiler lgkmcnt, no barrier).
__global__ __launch_bounds__(256) void k_gather_mm64(
    const float* __restrict__ H, const int2* __restrict__ ep,
    const int* __restrict__ rs, const float* __restrict__ dinv,
    const float* __restrict__ bias, const float* __restrict__ W,
    float* __restrict__ out, int N) {
  __shared__ float Ws[64][64];      // 16KB, [k][f]
  __shared__ float row[4][4][68];   // [wave][node][feat], 68-stride: conflict-free
  const int tid = threadIdx.x;
  for (int i = tid * 4; i < 4096; i += 1024)
    *(float4*)&((float*)Ws)[i] = *(const float4*)&W[i];
  __syncthreads();

  const int wv = tid >> 6, lane = tid & 63;
  const float bl = bias[lane];
  const int w0 = blockIdx.x * 16 + wv * 4;

#pragma unroll
  for (int q = 0; q < 4; ++q) {
    const int w = w0 + q;
    if (w < N) {
      const int s0 = rs[w], s1 = rs[w + 1];
      const float di = dinv[w];
      float acc = H[(size_t)w * 64 + lane] * di * di;
      int j = s0;
      for (; j + 3 < s1; j += 4) {
        const int2 p0 = ep[j + 0];
        const int2 p1 = ep[j + 1];
        const int2 p2 = ep[j + 2];
        const int2 p3 = ep[j + 3];
        const float h0 = H[(size_t)p0.x * 64 + lane];
        const float h1 = H[(size_t)p1.x * 64 + lane];
        const float h2 = H[(size_t)p2.x * 64 + lane];
        const float h3 = H[(size_t)p3.x * 64 + lane];
        acc = fmaf(h0, __int_as_float(p0.y), acc);
        acc = fmaf(h1, __int_as_float(p1.y), acc);
        acc = fmaf(h2, __int_as_float(p2.y), acc);
        acc = fmaf(h3, __int_as_float(p3.y), acc);
      }
      for (; j < s1; ++j) {
        const int2 p = ep[j];
        acc = fmaf(H[(size_t)p.x * 64 + lane], __int_as_float(p.y), acc);
      }
      row[wv][q][lane] = fmaxf(acc + bl, 0.f);
    }
  }

  // dot: 4 nodes interleaved; Ws reads shared across nodes
  float o[4] = {0.f, 0.f, 0.f, 0.f};
#pragma unroll
  for (int k4 = 0; k4 < 64; k4 += 4) {
    const float4 r0 = *(const float4*)&row[wv][0][k4];
    const float4 r1 = *(const float4*)&row[wv][1][k4];
    const float4 r2 = *(const float4*)&row[wv][2][k4];
    const float4 r3 = *(const float4*)&row[wv][3][k4];
    const float wa = Ws[k4 + 0][lane];
    const float wb = Ws[k4 + 1][lane];
    const float wc = Ws[k4 + 2][lane];
    const float wd = Ws[k4 + 3][lane];
    o[0] += r0.x * wa + r0.y * wb + r0.z * wc + r0.w * wd;
    o[1] += r1.x * wa + r1.y * wb + r1.z * wc + r1.w * wd;
    o[2] += r2.x * wa + r2.y * wb + r2.z * wc + r2.w * wd;
    o[3] += r3.x * wa + r3.y * wb + r3.z * wc + r3.w * wd;
  }
#pragma unroll
  for (int q = 0; q < 4; ++q) {
    const int w = w0 + q;
    if (w < N) out[(size_t)w * 64 + lane] = o[q];
  }
}

// Fused gather + relu(+bias) + [64x16] GEMM. lane = node-quadrant*16 + outfeat.
__global__ __launch_bounds__(256) void k_gather_mm16(
    const float* __restrict__ H, const int2* __restrict__ ep,
    const int* __restrict__ rs, const float* __restrict__ dinv,
    const float* __restrict__ bias, const float* __restrict__ W,
    float* __restrict__ out, int N) {
  __shared__ float Ws[64][16];      // 4KB, [k][f]
  __shared__ float row[4][4][68];
  const int tid = threadIdx.x;
  if (tid < 256) {
    const int i = tid * 4;
    if (i < 1024) *(float4*)&((float*)Ws)[i] = *(const float4*)&W[i];
  }
  __syncthreads();

  const int wv = tid >> 6, lane = tid & 63;
  const float bl = bias[lane];
  const int w0 = blockIdx.x * 16 + wv * 4;

#pragma unroll
  for (int q = 0; q < 4; ++q) {
    const int w = w0 + q;
    if (w < N) {
      const int s0 = rs[w], s1 = rs[w + 1];
      const float di = dinv[w];
      float acc = H[(size_t)w * 64 + lane] * di * di;
      int j = s0;
      for (; j + 3 < s1; j += 4) {
        const int2 p0 = ep[j + 0];
        const int2 p1 = ep[j + 1];
        const int2 p2 = ep[j + 2];
        const int2 p3 = ep[j + 3];
        const float h0 = H[(size_t)p0.x * 64 + lane];
        const float h1 = H[(size_t)p1.x * 64 + lane];
        const float h2 = H[(size_t)p2.x * 64 + lane];
        const float h3 = H[(size_t)p3.x * 64 + lane];
        acc = fmaf(h0, __int_as_float(p0.y), acc);
        acc = fmaf(h1, __int_as_float(p1.y), acc);
        acc = fmaf(h2, __int_as_float(p2.y), acc);
        acc = fmaf(h3, __int_as_float(p3.y), acc);
      }
      for (; j < s1; ++j) {
        const int2 p = ep[j];
        acc = fmaf(H[(size_t)p.x * 64 + lane], __int_as_float(p.y), acc);
      }
      row[wv][q][lane] = fmaxf(acc + bl, 0.f);
    }
  }

  const int q2 = lane >> 4, f = lane & 15;
  float o = 0.f;
#pragma unroll
  for (int k4 = 0; k4 < 64; k4 += 4) {
    const float4 rv = *(const float4*)&row[wv][q2][k4];
    o += rv.x * Ws[k4 + 0][f] + rv.y * Ws[k4 + 1][f] +
         rv.z * Ws[k4 + 2][f] + rv.w * Ws[k4 + 3][f];
  }
  const int w = w0 + q2;
  if (w < N) out[(size_t)w * 16 + f] = o;
}

// final: out = gather16(H3) + b3
__global__ __launch_bounds__(256) void k_gather16(
    const float* __restrict__ H, const int2* __restrict__ ep,
    const int* __restrict__ rs, const float* __restrict__ dinv,
    const float* __restrict__ b, float* __restrict__ out, int N) {
  const int t = blockIdx.x * blockDim.x + threadIdx.x;
  if (t >= N * 16) return;
  const int n = t >> 4;
  const int f = t & 15;
  const int s0 = rs[n], s1 = rs[n + 1];
  const float di = dinv[n];
  float acc = H[(size_t)n * 16 + f] * di * di;
  for (int j = s0; j < s1; ++j) {
    const int2 p = ep[j];
    acc = fmaf(H[(size_t)p.x * 16 + f], __int_as_float(p.y), acc);
  }
  out[(size_t)n * 16 + f] = acc + b[f];
}

extern "C" void kernel_launch(void* const* d_in, const int* in_sizes, int n_in,
                              void* d_out, int out_size, void* d_ws, size_t ws_size,
                              hipStream_t stream) {
  const float* features = (const float*)d_in[0];
  const int* edge_index = (const int*)d_in[1];
  const float* ew = (const float*)d_in[2];
  const float* W1 = (const float*)d_in[3];
  const float* b1 = (const float*)d_in[4];
  const float* W2 = (const float*)d_in[5];
  const float* b2 = (const float*)d_in[6];
  const float* W3 = (const float*)d_in[7];
  const float* b3 = (const float*)d_in[8];

  const int N = NNODES;
  const int E = NEDGES;
  const int* src = edge_index;
  const int* dst = edge_index + E;

  // ws: ep 2E | H1 N*64 | H2 N*64 | BH 4096x8s | BL 4096x8s | dinv N | cnt N | rs N+1 | bsums 256
  int2* ep = (int2*)d_ws;
  float* H1 = (float*)(ep + E);
  float* H2 = H1 + (size_t)N * 64;
  s16x8_t* BH = (s16x8_t*)(H2 + (size_t)N * 64);
  s16x8_t* BL = BH + 4096;
  float* dinv = (float*)(BL + 4096);
  int* cnt = (int*)(dinv + N);
  int* rs = cnt + N;
  int* bsums = rs + N + 1;
  float* H3 = H1;  // reuse H1 region for the N x 16 layer-3 output

  const int B = 256;
  const int gN = (N + B - 1) / B;
  const int gE = (E + B - 1) / B;
  const int g128 = (N + 127) / 128;
  const int gf = (N + 15) / 16;
  const int nb1 = (N + SCAN_B - 1) / SCAN_B;

  // CSR build + norms
  k_init<<<gN, B, 0, stream>>>(dinv, cnt, N);
  k_deg_cnt<<<gE, B, 0, stream>>>(dst, ew, dinv, cnt, E);
  k_scan1<<<nb1, SCAN_B, 0, stream>>>(cnt, rs, bsums, dinv, N);
  k_scan2<<<1, 256, 0, stream>>>(bsums, nb1);
  k_scan3<<<gN, B, 0, stream>>>(rs, bsums, cnt, N, E);
  k_fill<<<gE, B, 0, stream>>>(src, dst, ew, dinv, rs, cnt, ep, E);

  // W1 fragment precompute + layer 1 GEMM
  k_prep_w1<<<16, 256, 0, stream>>>(W1, BH, BL);
  k_gemm1_mfma<<<g128, 256, 0, stream>>>(features, BH, BL, H1, N);

  // layer 1 gather + (relu,b1) + GEMM2 fused -> H2
  k_gather_mm64<<<gf, 256, 0, stream>>>(H1, ep, rs, dinv, b1, W2, H2, N);
  // layer 2 gather + (relu,b2) + GEMM3 fused -> H3 (N x 16)
  k_gather_mm16<<<gf, 256, 0, stream>>>(H2, ep, rs, dinv, b2, W3, H3, N);
  // layer 3 gather + b3 -> out
  k_gather16<<<(N * 16 + B - 1) / B, B, 0, stream>>>(H3, ep, rs, dinv, b3, (float*)d_out, N);
}

// Round 12
// 675.545 us; speedup vs baseline: 1.2510x; 1.2510x over previous
//
#include <hip/hip_runtime.h>

// GCN 3-layer forward, MI355X (gfx950) — R12.
// R12 vs R11 (845 us, regression): fused gather+GEMM kernels restructured from
// 4 nodes/wave (serialized, occupancy 10%, 295 us) to 1 node/wave — restores
// R9's 100k-wave parallelism while keeping the fusion's traffic savings.

#define NNODES 100000
#define NEDGES 1000000
#define INF 512
#define SCAN_B 512

typedef float f32x4_t __attribute__((ext_vector_type(4)));
typedef short s16x8_t __attribute__((ext_vector_type(8)));

__device__ __forceinline__ unsigned short f2bf(float x) {
  unsigned u = __float_as_uint(x);
  return (unsigned short)((u + 0x7FFFu + ((u >> 16) & 1u)) >> 16);
}
__device__ __forceinline__ float bf2f(unsigned short h) {
  return __uint_as_float(((unsigned)h) << 16);
}

__global__ void k_init(float* __restrict__ deg, int* __restrict__ cnt, int n) {
  int i = blockIdx.x * blockDim.x + threadIdx.x;
  if (i < n) { deg[i] = 1.0f; cnt[i] = 0; }
}

__global__ void k_deg_cnt(const int* __restrict__ dst, const float* __restrict__ ew,
                          float* __restrict__ deg, int* __restrict__ cnt, int E) {
  int e = blockIdx.x * blockDim.x + threadIdx.x;
  if (e < E) {
    int d = dst[e];
    atomicAdd(&deg[d], ew[e]);
    atomicAdd(&cnt[d], 1);
  }
}

// exclusive scan stage 1 + fused dinv (deg -> 1/sqrt(deg))
__global__ __launch_bounds__(SCAN_B) void k_scan1(const int* __restrict__ cnt,
                                                  int* __restrict__ rs,
                                                  int* __restrict__ bsums,
                                                  float* __restrict__ deg, int n) {
  __shared__ int s[SCAN_B];
  const int t = threadIdx.x;
  const int i = blockIdx.x * SCAN_B + t;
  int v = (i < n) ? cnt[i] : 0;
  s[t] = v;
  __syncthreads();
  int acc = v;
#pragma unroll
  for (int off = 1; off < SCAN_B; off <<= 1) {
    int add = (t >= off) ? s[t - off] : 0;
    __syncthreads();
    acc += add;
    s[t] = acc;
    __syncthreads();
  }
  if (i < n) {
    rs[i] = acc - v;
    float d = deg[i];
    deg[i] = d > 0.f ? 1.0f / sqrtf(d) : 0.f;
  }
  if (t == SCAN_B - 1) bsums[blockIdx.x] = acc;
}

__global__ __launch_bounds__(256) void k_scan2(int* __restrict__ bsums, int nb) {
  __shared__ int s[256];
  const int t = threadIdx.x;
  int v = (t < nb) ? bsums[t] : 0;
  s[t] = v;
  __syncthreads();
  int acc = v;
#pragma unroll
  for (int off = 1; off < 256; off <<= 1) {
    int add = (t >= off) ? s[t - off] : 0;
    __syncthreads();
    acc += add;
    s[t] = acc;
    __syncthreads();
  }
  if (t < nb) bsums[t] = acc - v;
}

__global__ void k_scan3(int* __restrict__ rs, const int* __restrict__ bsums,
                        int* __restrict__ cnt, int n, int E) {
  int i = blockIdx.x * blockDim.x + threadIdx.x;
  if (i < n) {
    rs[i] += bsums[i / SCAN_B];
    cnt[i] = 0;
  }
  if (i == 0) rs[n] = E;
}

__global__ void k_fill(const int* __restrict__ src, const int* __restrict__ dst,
                       const float* __restrict__ ew, const float* __restrict__ dinv,
                       const int* __restrict__ rs, int* __restrict__ cur,
                       int2* __restrict__ ep, int E) {
  int e = blockIdx.x * blockDim.x + threadIdx.x;
  if (e < E) {
    const int s = src[e], d = dst[e];
    const int pos = rs[d] + atomicAdd(&cur[d], 1);
    const float nm = dinv[s] * ew[e] * dinv[d];
    ep[pos] = make_int2(s, __float_as_int(nm));
  }
}

// W1[512][64] -> bf16 hi/lo fragments in the 16x16x32 MFMA B layout (R9-verified).
__global__ __launch_bounds__(256) void k_prep_w1(const float* __restrict__ W,
                                                 s16x8_t* __restrict__ BH,
                                                 s16x8_t* __restrict__ BL) {
  const int t = blockIdx.x * 256 + threadIdx.x;  // 0..4095
  const int kstep = t >> 8, rem = t & 255, bc = rem >> 6, l = rem & 63;
  const int kg = l >> 4, m0 = l & 15;
  s16x8_t bh, blo;
#pragma unroll
  for (int i = 0; i < 8; ++i) {
    const float w = W[(size_t)(kstep * 32 + kg * 8 + i) * 64 + bc * 16 + m0];
    const unsigned short h = f2bf(w);
    bh[i] = (short)h;
    blo[i] = (short)f2bf(w - bf2f(h));
  }
  BH[t] = bh;
  BL[t] = blo;
}

// GEMM1: H[M,64] = A[M,512] @ W1, bf16x3 MFMA, B-frags preconverted in global.
__global__ __launch_bounds__(256) void k_gemm1_mfma(
    const float* __restrict__ A, const s16x8_t* __restrict__ BH,
    const s16x8_t* __restrict__ BL, float* __restrict__ C, int M) {
  __shared__ float As[128][36];
  const int tid = threadIdx.x;
  const int bm = blockIdx.x * 128;
  const int wv = tid >> 6;
  const int l = tid & 63;
  const int m0 = l & 15;
  const int kg = l >> 4;

  f32x4_t acc[2][4];
#pragma unroll
  for (int r = 0; r < 2; ++r)
#pragma unroll
    for (int c = 0; c < 4; ++c) acc[r][c] = (f32x4_t)0.f;

  for (int k0 = 0; k0 < INF; k0 += 32) {
    s16x8_t bh[4], bl[4];
    const int kbase = (k0 >> 5) * 256 + l;
#pragma unroll
    for (int c = 0; c < 4; ++c) {
      bh[c] = BH[kbase + c * 64];
      bl[c] = BL[kbase + c * 64];
    }
#pragma unroll
    for (int i = 0; i < 4; ++i) {
      const int idx = i * 256 + tid;
      const int row = idx >> 3;
      const int kq = (idx & 7) << 2;
      const int grow = bm + row;
      float4 v = make_float4(0.f, 0.f, 0.f, 0.f);
      if (grow < M) v = *(const float4*)(A + (size_t)grow * INF + k0 + kq);
      *(float4*)&As[row][kq] = v;
    }
    __syncthreads();

    s16x8_t ahi[2], alo[2];
#pragma unroll
    for (int r = 0; r < 2; ++r) {
      const float* ap = &As[wv * 32 + r * 16 + m0][kg * 8];
      const float4 x0 = *(const float4*)ap;
      const float4 x1 = *(const float4*)(ap + 4);
      const float xs[8] = {x0.x, x0.y, x0.z, x0.w, x1.x, x1.y, x1.z, x1.w};
#pragma unroll
      for (int i = 0; i < 8; ++i) {
        const unsigned short h = f2bf(xs[i]);
        ahi[r][i] = (short)h;
        alo[r][i] = (short)f2bf(xs[i] - bf2f(h));
      }
    }
#pragma unroll
    for (int c = 0; c < 4; ++c) {
#pragma unroll
      for (int r = 0; r < 2; ++r) {
        acc[r][c] = __builtin_amdgcn_mfma_f32_16x16x32_bf16(ahi[r], bh[c], acc[r][c], 0, 0, 0);
        acc[r][c] = __builtin_amdgcn_mfma_f32_16x16x32_bf16(alo[r], bh[c], acc[r][c], 0, 0, 0);
        acc[r][c] = __builtin_amdgcn_mfma_f32_16x16x32_bf16(ahi[r], bl[c], acc[r][c], 0, 0, 0);
      }
    }
    __syncthreads();
  }

#pragma unroll
  for (int r = 0; r < 2; ++r) {
    const int rowbase = bm + wv * 32 + r * 16 + (l >> 4) * 4;
#pragma unroll
    for (int j = 0; j < 4; ++j) {
      const int row = rowbase + j;
      if (row < M) {
#pragma unroll
        for (int c = 0; c < 4; ++c)
          C[(size_t)row * 64 + c * 16 + m0] = acc[r][c][j];
      }
    }
  }
}

// Fused gather + relu(+bias) + [64x64] GEMM. ONE node per wave (R12 fix):
// 4 nodes/block, grid N/4 -> 100k waves, same MLP as R9's gather64.
__global__ __launch_bounds__(256) void k_gather_mm64(
    const float* __restrict__ H, const int2* __restrict__ ep,
    const int* __restrict__ rs, const float* __restrict__ dinv,
    const float* __restrict__ bias, const float* __restrict__ W,
    float* __restrict__ out, int N) {
  __shared__ float Ws[64][64];    // 16KB, [k][f]
  __shared__ float row[4][68];    // per-wave row, 68-stride
  const int tid = threadIdx.x;
  for (int i = tid * 4; i < 4096; i += 1024)
    *(float4*)&((float*)Ws)[i] = *(const float4*)&W[i];
  __syncthreads();

  const int wv = tid >> 6, lane = tid & 63;
  const int w = blockIdx.x * 4 + wv;
  if (w >= N) return;

  const int s0 = rs[w], s1 = rs[w + 1];
  const float di = dinv[w];
  float acc = H[(size_t)w * 64 + lane] * di * di;
  int j = s0;
  for (; j + 3 < s1; j += 4) {
    const int2 p0 = ep[j + 0];
    const int2 p1 = ep[j + 1];
    const int2 p2 = ep[j + 2];
    const int2 p3 = ep[j + 3];
    const float h0 = H[(size_t)p0.x * 64 + lane];
    const float h1 = H[(size_t)p1.x * 64 + lane];
    const float h2 = H[(size_t)p2.x * 64 + lane];
    const float h3 = H[(size_t)p3.x * 64 + lane];
    acc = fmaf(h0, __int_as_float(p0.y), acc);
    acc = fmaf(h1, __int_as_float(p1.y), acc);
    acc = fmaf(h2, __int_as_float(p2.y), acc);
    acc = fmaf(h3, __int_as_float(p3.y), acc);
  }
  for (; j < s1; ++j) {
    const int2 p = ep[j];
    acc = fmaf(H[(size_t)p.x * 64 + lane], __int_as_float(p.y), acc);
  }
  row[wv][lane] = fmaxf(acc + bias[lane], 0.f);  // intra-wave RAW (lgkmcnt)

  float o = 0.f;
#pragma unroll
  for (int k4 = 0; k4 < 64; k4 += 4) {
    const float4 rv = *(const float4*)&row[wv][k4];  // wave-broadcast, free
    o += rv.x * Ws[k4 + 0][lane] + rv.y * Ws[k4 + 1][lane] +
         rv.z * Ws[k4 + 2][lane] + rv.w * Ws[k4 + 3][lane];
  }
  out[(size_t)w * 64 + lane] = o;
}

// Fused gather + relu(+bias) + [64x16] GEMM. ONE node per wave; dot uses
// per-quadrant partials + 2x shfl_xor reduce.
__global__ __launch_bounds__(256) void k_gather_mm16(
    const float* __restrict__ H, const int2* __restrict__ ep,
    const int* __restrict__ rs, const float* __restrict__ dinv,
    const float* __restrict__ bias, const float* __restrict__ W,
    float* __restrict__ out, int N) {
  __shared__ float Ws[64][16];    // 4KB
  __shared__ float row[4][68];
  const int tid = threadIdx.x;
  {
    const int i = tid * 4;
    if (i < 1024) *(float4*)&((float*)Ws)[i] = *(const float4*)&W[i];
  }
  __syncthreads();

  const int wv = tid >> 6, lane = tid & 63;
  const int w = blockIdx.x * 4 + wv;
  if (w >= N) return;

  const int s0 = rs[w], s1 = rs[w + 1];
  const float di = dinv[w];
  float acc = H[(size_t)w * 64 + lane] * di * di;
  int j = s0;
  for (; j + 3 < s1; j += 4) {
    const int2 p0 = ep[j + 0];
    const int2 p1 = ep[j + 1];
    const int2 p2 = ep[j + 2];
    const int2 p3 = ep[j + 3];
    const float h0 = H[(size_t)p0.x * 64 + lane];
    const float h1 = H[(size_t)p1.x * 64 + lane];
    const float h2 = H[(size_t)p2.x * 64 + lane];
    const float h3 = H[(size_t)p3.x * 64 + lane];
    acc = fmaf(h0, __int_as_float(p0.y), acc);
    acc = fmaf(h1, __int_as_float(p1.y), acc);
    acc = fmaf(h2, __int_as_float(p2.y), acc);
    acc = fmaf(h3, __int_as_float(p3.y), acc);
  }
  for (; j < s1; ++j) {
    const int2 p = ep[j];
    acc = fmaf(H[(size_t)p.x * 64 + lane], __int_as_float(p.y), acc);
  }
  row[wv][lane] = fmaxf(acc + bias[lane], 0.f);

  const int kq = lane >> 4, f = lane & 15;
  float p = 0.f;
#pragma unroll
  for (int i = 0; i < 16; i += 4) {
    const float4 rv = *(const float4*)&row[wv][kq * 16 + i];
    p += rv.x * Ws[kq * 16 + i + 0][f] + rv.y * Ws[kq * 16 + i + 1][f] +
         rv.z * Ws[kq * 16 + i + 2][f] + rv.w * Ws[kq * 16 + i + 3][f];
  }
  p += __shfl_xor(p, 16);
  p += __shfl_xor(p, 32);
  if (kq == 0) out[(size_t)w * 16 + f] = p;
}

// final: out = gather16(H3) + b3
__global__ __launch_bounds__(256) void k_gather16(
    const float* __restrict__ H, const int2* __restrict__ ep,
    const int* __restrict__ rs, const float* __restrict__ dinv,
    const float* __restrict__ b, float* __restrict__ out, int N) {
  const int t = blockIdx.x * blockDim.x + threadIdx.x;
  if (t >= N * 16) return;
  const int n = t >> 4;
  const int f = t & 15;
  const int s0 = rs[n], s1 = rs[n + 1];
  const float di = dinv[n];
  float acc = H[(size_t)n * 16 + f] * di * di;
  for (int j = s0; j < s1; ++j) {
    const int2 p = ep[j];
    acc = fmaf(H[(size_t)p.x * 16 + f], __int_as_float(p.y), acc);
  }
  out[(size_t)n * 16 + f] = acc + b[f];
}

extern "C" void kernel_launch(void* const* d_in, const int* in_sizes, int n_in,
                              void* d_out, int out_size, void* d_ws, size_t ws_size,
                              hipStream_t stream) {
  const float* features = (const float*)d_in[0];
  const int* edge_index = (const int*)d_in[1];
  const float* ew = (const float*)d_in[2];
  const float* W1 = (const float*)d_in[3];
  const float* b1 = (const float*)d_in[4];
  const float* W2 = (const float*)d_in[5];
  const float* b2 = (const float*)d_in[6];
  const float* W3 = (const float*)d_in[7];
  const float* b3 = (const float*)d_in[8];

  const int N = NNODES;
  const int E = NEDGES;
  const int* src = edge_index;
  const int* dst = edge_index + E;

  // ws: ep 2E | H1 N*64 | H2 N*64 | BH 4096 | BL 4096 | dinv N | cnt N | rs N+1 | bsums 256
  int2* ep = (int2*)d_ws;
  float* H1 = (float*)(ep + E);
  float* H2 = H1 + (size_t)N * 64;
  s16x8_t* BH = (s16x8_t*)(H2 + (size_t)N * 64);
  s16x8_t* BL = BH + 4096;
  float* dinv = (float*)(BL + 4096);
  int* cnt = (int*)(dinv + N);
  int* rs = cnt + N;
  int* bsums = rs + N + 1;
  float* H3 = H1;  // reuse H1 region for the N x 16 layer-3 output

  const int B = 256;
  const int gN = (N + B - 1) / B;
  const int gE = (E + B - 1) / B;
  const int g128 = (N + 127) / 128;
  const int g4 = (N + 3) / 4;   // 1 node per wave, 4 waves per block
  const int nb1 = (N + SCAN_B - 1) / SCAN_B;

  // CSR build + norms
  k_init<<<gN, B, 0, stream>>>(dinv, cnt, N);
  k_deg_cnt<<<gE, B, 0, stream>>>(dst, ew, dinv, cnt, E);
  k_scan1<<<nb1, SCAN_B, 0, stream>>>(cnt, rs, bsums, dinv, N);
  k_scan2<<<1, 256, 0, stream>>>(bsums, nb1);
  k_scan3<<<gN, B, 0, stream>>>(rs, bsums, cnt, N, E);
  k_fill<<<gE, B, 0, stream>>>(src, dst, ew, dinv, rs, cnt, ep, E);

  // W1 fragment precompute + layer 1 GEMM
  k_prep_w1<<<16, 256, 0, stream>>>(W1, BH, BL);
  k_gemm1_mfma<<<g128, 256, 0, stream>>>(features, BH, BL, H1, N);

  // layer 1 gather + (relu,b1) + GEMM2 fused -> H2
  k_gather_mm64<<<g4, 256, 0, stream>>>(H1, ep, rs, dinv, b1, W2, H2, N);
  // layer 2 gather + (relu,b2) + GEMM3 fused -> H3 (N x 16)
  k_gather_mm16<<<g4, 256, 0, stream>>>(H2, ep, rs, dinv, b2, W3, H3, N);
  // layer 3 gather + b3 -> out
  k_gather16<<<(N * 16 + B - 1) / B, B, 0, stream>>>(H3, ep, rs, dinv, b3, (float*)d_out, N);
}